// Round 1
// baseline (103.216 us; speedup 1.0000x reference)
//
#include <hip/hip_runtime.h>
#include <hip/hip_bf16.h>

// Problem dims (fixed by reference): B=64 S=256 F=4 V=50257 H=768 D=512
#define M_TOT 16384   // B*S
#define K_TOT 768     // H
#define N_TOT 512     // D

typedef __attribute__((ext_vector_type(8))) __bf16 bf16x8;
typedef __attribute__((ext_vector_type(4))) float f32x4;

static __device__ __forceinline__ ushort f2bf(float x) {
  // round-to-nearest-even bf16 (no NaN inputs here)
  union { float f; unsigned int u; } v; v.f = x;
  unsigned int r = v.u + 0x7fffu + ((v.u >> 16) & 1u);
  return (ushort)(r >> 16);
}

// ---------------------------------------------------------------------------
// Kernel 1: gather + masked mean -> bf16 activation A[16384][768]
// one wave per word row; lane covers cols {c*256 + lane*4 + j}, c=0..2
// ---------------------------------------------------------------------------
__global__ __launch_bounds__(256) void gather_mean_kernel(
    const int* __restrict__ words, const float* __restrict__ E,
    ushort* __restrict__ A) {
  const int row  = blockIdx.x * 4 + (threadIdx.x >> 6);
  const int lane = threadIdx.x & 63;
  const int4 w4 = *reinterpret_cast<const int4*>(words + (size_t)row * 4);
  const int ids[4] = {w4.x, w4.y, w4.z, w4.w};

  float a[12];
#pragma unroll
  for (int i = 0; i < 12; ++i) a[i] = 0.f;
  float cnt = 0.f;

#pragma unroll
  for (int f = 0; f < 4; ++f) {
    const int id = ids[f];
    if (id != 0) {  // PAD==0; wave-uniform branch
      const float4* __restrict__ src =
          reinterpret_cast<const float4*>(E + (size_t)id * K_TOT);
#pragma unroll
      for (int c = 0; c < 3; ++c) {
        const float4 v = src[c * 64 + lane];
        a[c * 4 + 0] += v.x; a[c * 4 + 1] += v.y;
        a[c * 4 + 2] += v.z; a[c * 4 + 3] += v.w;
      }
      cnt += 1.f;
    }
  }
  const float s = (cnt > 0.f) ? (1.f / cnt) : 0.f;  // fully-padded word -> 0
  ushort* dst = A + (size_t)row * K_TOT;
#pragma unroll
  for (int c = 0; c < 3; ++c) {
    ushort4 o;
    o.x = f2bf(a[c * 4 + 0] * s);
    o.y = f2bf(a[c * 4 + 1] * s);
    o.z = f2bf(a[c * 4 + 2] * s);
    o.w = f2bf(a[c * 4 + 3] * s);
    *reinterpret_cast<ushort4*>(dst + c * 256 + lane * 4) = o;
  }
}

// ---------------------------------------------------------------------------
// Kernel 2: W[768][512] f32  ->  Wt[512][768] bf16 (transpose + convert)
// 64x64 tiles via padded LDS
// ---------------------------------------------------------------------------
__global__ __launch_bounds__(256) void wt_kernel(const float* __restrict__ W,
                                                 ushort* __restrict__ Wt) {
  __shared__ float tile[64][65];
  const int t  = threadIdx.x;
  const int k0 = blockIdx.x * 64;
  const int n0 = blockIdx.y * 64;
#pragma unroll
  for (int i = 0; i < 4; ++i) {
    const int idx = t + i * 256;
    const int r = idx >> 4;
    const int c = (idx & 15) * 4;
    const float4 v =
        *reinterpret_cast<const float4*>(W + (size_t)(k0 + r) * N_TOT + n0 + c);
    tile[r][c + 0] = v.x; tile[r][c + 1] = v.y;
    tile[r][c + 2] = v.z; tile[r][c + 3] = v.w;
  }
  __syncthreads();
#pragma unroll
  for (int i = 0; i < 4; ++i) {
    const int idx = t + i * 256;
    const int rn = idx >> 4;
    const int ck = (idx & 15) * 4;
    ushort4 o;
    o.x = f2bf(tile[ck + 0][rn]);
    o.y = f2bf(tile[ck + 1][rn]);
    o.z = f2bf(tile[ck + 2][rn]);
    o.w = f2bf(tile[ck + 3][rn]);
    *reinterpret_cast<ushort4*>(Wt + (size_t)(n0 + rn) * K_TOT + k0 + ck) = o;
  }
}

// ---------------------------------------------------------------------------
// Kernel 3: bf16 MFMA GEMM  out[16384][512] = A[16384][768] @ Wt^T + bias
// A row-major [M][K]; Bt row-major [N][K]. Tile 128x128, BK=64, 4 waves.
// XOR-swizzled LDS (byte ^= (row&7)<<4 equivalent, slot granularity 16B).
// ---------------------------------------------------------------------------
__global__ __launch_bounds__(256) void gemm_kernel(
    const ushort* __restrict__ A, const ushort* __restrict__ Bt,
    const float* __restrict__ bias, float* __restrict__ out) {
  __shared__ ushort Al[128 * 64];
  __shared__ ushort Bl[128 * 64];
  const int t    = threadIdx.x;
  const int lane = t & 63;
  const int w    = t >> 6;
  const int bm   = blockIdx.x >> 2;   // 0..127
  const int bn   = blockIdx.x & 3;    // 0..3
  const int wr   = w >> 1;            // 0..1
  const int wc   = w & 1;             // 0..1

  f32x4 acc[4][4];
#pragma unroll
  for (int m = 0; m < 4; ++m)
#pragma unroll
    for (int n = 0; n < 4; ++n) acc[m][n] = (f32x4){0.f, 0.f, 0.f, 0.f};

  // staging: thread t loads 16B chunk (row = t>>3 + i*32, seg = t&7) of each
  // 128x64 tile; writes LDS slot = seg ^ (row&7)  (row&7 invariant over i)
  const int srow = t >> 3;
  const int sseg = t & 7;
  const int wslot = sseg ^ (srow & 7);
  const ushort* aptr = A  + (size_t)(bm * 128 + srow) * K_TOT + sseg * 8;
  const ushort* bptr = Bt + (size_t)(bn * 128 + srow) * K_TOT + sseg * 8;
  const int ldsWoff = srow * 64 + wslot * 8;  // elems

  uint4 avreg[4], bvreg[4];
#pragma unroll
  for (int i = 0; i < 4; ++i) {
    avreg[i] = *reinterpret_cast<const uint4*>(aptr + (size_t)i * 32 * K_TOT);
    bvreg[i] = *reinterpret_cast<const uint4*>(bptr + (size_t)i * 32 * K_TOT);
  }

  for (int kt = 0; kt < K_TOT / 64; ++kt) {
    __syncthreads();  // prior compute done reading LDS
#pragma unroll
    for (int i = 0; i < 4; ++i) {
      *reinterpret_cast<uint4*>(&Al[ldsWoff + i * 2048]) = avreg[i];
      *reinterpret_cast<uint4*>(&Bl[ldsWoff + i * 2048]) = bvreg[i];
    }
    __syncthreads();
    if (kt + 1 < K_TOT / 64) {  // prefetch next K-tile into regs
      const ushort* ap = aptr + (kt + 1) * 64;
      const ushort* bp = bptr + (kt + 1) * 64;
#pragma unroll
      for (int i = 0; i < 4; ++i) {
        avreg[i] = *reinterpret_cast<const uint4*>(ap + (size_t)i * 32 * K_TOT);
        bvreg[i] = *reinterpret_cast<const uint4*>(bp + (size_t)i * 32 * K_TOT);
      }
    }
#pragma unroll
    for (int kk = 0; kk < 2; ++kk) {
      bf16x8 af[4], bf_[4];
      const int segk = kk * 4 + (lane >> 4);
#pragma unroll
      for (int m = 0; m < 4; ++m) {
        const int r = wr * 64 + m * 16 + (lane & 15);
        af[m] = *reinterpret_cast<const bf16x8*>(
            &Al[r * 64 + ((segk ^ (r & 7)) * 8)]);
      }
#pragma unroll
      for (int n = 0; n < 4; ++n) {
        const int r = wc * 64 + n * 16 + (lane & 15);
        bf_[n] = *reinterpret_cast<const bf16x8*>(
            &Bl[r * 64 + ((segk ^ (r & 7)) * 8)]);
      }
#pragma unroll
      for (int m = 0; m < 4; ++m)
#pragma unroll
        for (int n = 0; n < 4; ++n)
          acc[m][n] = __builtin_amdgcn_mfma_f32_16x16x32_bf16(
              af[m], bf_[n], acc[m][n], 0, 0, 0);
    }
  }

  // epilogue: C col = lane&15 (+16n), row = (lane>>4)*4 + j (+16m)
  const int colBase = bn * 128 + wc * 64 + (lane & 15);
  const int rowBase = bm * 128 + wr * 64 + ((lane >> 4) << 2);
#pragma unroll
  for (int n = 0; n < 4; ++n) {
    const float bv = bias[colBase + n * 16];
#pragma unroll
    for (int m = 0; m < 4; ++m) {
#pragma unroll
      for (int j = 0; j < 4; ++j) {
        out[(size_t)(rowBase + m * 16 + j) * N_TOT + colBase + n * 16] =
            acc[m][n][j] + bv;
      }
    }
  }
}

// ---------------------------------------------------------------------------
extern "C" void kernel_launch(void* const* d_in, const int* in_sizes, int n_in,
                              void* d_out, int out_size, void* d_ws,
                              size_t ws_size, hipStream_t stream) {
  const int*   words = (const int*)d_in[0];
  const float* E     = (const float*)d_in[1];
  const float* W     = (const float*)d_in[2];
  const float* b     = (const float*)d_in[3];
  float* out = (float*)d_out;

  ushort* Aws  = (ushort*)d_ws;                       // 16384*768 bf16
  ushort* Wtws = Aws + (size_t)M_TOT * K_TOT;         // 512*768 bf16

  hipLaunchKernelGGL(gather_mean_kernel, dim3(M_TOT / 4), dim3(256), 0, stream,
                     words, E, Aws);
  hipLaunchKernelGGL(wt_kernel, dim3(K_TOT / 64, N_TOT / 64), dim3(256), 0,
                     stream, W, Wtws);
  hipLaunchKernelGGL(gemm_kernel, dim3((M_TOT / 128) * (N_TOT / 128)),
                     dim3(256), 0, stream, Aws, Wtws, b, out);
}

// Round 2
// 62.485 us; speedup vs baseline: 1.6518x; 1.6518x over previous
//
#include <hip/hip_runtime.h>
#include <hip/hip_bf16.h>

// Problem dims (fixed by reference): B=64 S=256 F=4 V=50257 H=768 D=512
#define M_TOT 16384   // B*S
#define K_TOT 768     // H
#define N_TOT 512     // D

typedef __attribute__((ext_vector_type(8))) __bf16 bf16x8;
typedef __attribute__((ext_vector_type(4))) float f32x4;

static __device__ __forceinline__ ushort f2bf(float x) {
  // round-to-nearest-even bf16 (no NaN inputs here)
  union { float f; unsigned int u; } v; v.f = x;
  unsigned int r = v.u + 0x7fffu + ((v.u >> 16) & 1u);
  return (ushort)(r >> 16);
}

// async global->LDS, 16B per lane; lds dest is wave-uniform base + lane*16
static __device__ __forceinline__ void load_lds16(const ushort* g, ushort* l) {
  __builtin_amdgcn_global_load_lds(
      (const __attribute__((address_space(1))) void*)g,
      (__attribute__((address_space(3))) void*)l, 16, 0, 0);
}

// ---------------------------------------------------------------------------
// Kernel 1 (merged): blocks [0, 4096): gather + masked mean -> bf16 A[16384][768]
//                    blocks [4096, 4192): W[768][512] f32 -> Wt[512][768] bf16
// ---------------------------------------------------------------------------
__global__ __launch_bounds__(256) void prep_kernel(
    const int* __restrict__ words, const float* __restrict__ E,
    const float* __restrict__ W, ushort* __restrict__ A,
    ushort* __restrict__ Wt) {
  const int bid = blockIdx.x;
  const int t = threadIdx.x;
  if (bid < M_TOT / 4) {
    // ---- gather + masked mean: one wave per word row ----
    const int row  = bid * 4 + (t >> 6);
    const int lane = t & 63;
    const int4 w4 = *reinterpret_cast<const int4*>(words + (size_t)row * 4);
    const int ids[4] = {w4.x, w4.y, w4.z, w4.w};

    float a[12];
#pragma unroll
    for (int i = 0; i < 12; ++i) a[i] = 0.f;
    float cnt = 0.f;

#pragma unroll
    for (int f = 0; f < 4; ++f) {
      const int id = ids[f];
      if (id != 0) {  // PAD==0; wave-uniform branch
        const float4* __restrict__ src =
            reinterpret_cast<const float4*>(E + (size_t)id * K_TOT);
#pragma unroll
        for (int c = 0; c < 3; ++c) {
          const float4 v = src[c * 64 + lane];
          a[c * 4 + 0] += v.x; a[c * 4 + 1] += v.y;
          a[c * 4 + 2] += v.z; a[c * 4 + 3] += v.w;
        }
        cnt += 1.f;
      }
    }
    const float s = (cnt > 0.f) ? (1.f / cnt) : 0.f;  // fully-padded word -> 0
    ushort* dst = A + (size_t)row * K_TOT;
#pragma unroll
    for (int c = 0; c < 3; ++c) {
      ushort4 o;
      o.x = f2bf(a[c * 4 + 0] * s);
      o.y = f2bf(a[c * 4 + 1] * s);
      o.z = f2bf(a[c * 4 + 2] * s);
      o.w = f2bf(a[c * 4 + 3] * s);
      *reinterpret_cast<ushort4*>(dst + c * 256 + lane * 4) = o;
    }
  } else {
    // ---- transpose + bf16-convert W -> Wt ----
    __shared__ float tile[64][65];
    const int b2 = bid - M_TOT / 4;
    const int k0 = (b2 % (K_TOT / 64)) * 64;
    const int n0 = (b2 / (K_TOT / 64)) * 64;
#pragma unroll
    for (int i = 0; i < 4; ++i) {
      const int idx = t + i * 256;
      const int r = idx >> 4;
      const int c = (idx & 15) * 4;
      const float4 v = *reinterpret_cast<const float4*>(
          W + (size_t)(k0 + r) * N_TOT + n0 + c);
      tile[r][c + 0] = v.x; tile[r][c + 1] = v.y;
      tile[r][c + 2] = v.z; tile[r][c + 3] = v.w;
    }
    __syncthreads();
#pragma unroll
    for (int i = 0; i < 4; ++i) {
      const int idx = t + i * 256;
      const int rn = idx >> 4;
      const int ck = (idx & 15) * 4;
      ushort4 o;
      o.x = f2bf(tile[ck + 0][rn]);
      o.y = f2bf(tile[ck + 1][rn]);
      o.z = f2bf(tile[ck + 2][rn]);
      o.w = f2bf(tile[ck + 3][rn]);
      *reinterpret_cast<ushort4*>(Wt + (size_t)(n0 + rn) * K_TOT + k0 + ck) = o;
    }
  }
}

// ---------------------------------------------------------------------------
// Kernel 2: bf16 MFMA GEMM  out[16384][512] = A @ Wt^T + bias
// m97 structure: 128x128 tile, BK=64, 4 waves, global_load_lds width-16,
// linear LDS [128][64], single buffer, 2-barrier K-loop.
// ---------------------------------------------------------------------------
__global__ __launch_bounds__(256) void gemm_kernel(
    const ushort* __restrict__ A, const ushort* __restrict__ Bt,
    const float* __restrict__ bias, float* __restrict__ out) {
  __shared__ ushort Al[128 * 64];
  __shared__ ushort Bl[128 * 64];
  const int t    = threadIdx.x;
  const int lane = t & 63;
  const int w    = t >> 6;
  const int bm   = blockIdx.x >> 2;   // 0..127
  const int bn   = blockIdx.x & 3;    // 0..3
  const int wr   = w >> 1;            // 0..1
  const int wc   = w & 1;             // 0..1

  f32x4 acc[4][4];
#pragma unroll
  for (int m = 0; m < 4; ++m)
#pragma unroll
    for (int n = 0; n < 4; ++n) acc[m][n] = (f32x4){0.f, 0.f, 0.f, 0.f};

  // staging: chunk c = i*256 + t covers row = c>>3 (=i*32 + t>>3), seg = c&7.
  // LDS elem offset = c*8  -> linear [128][64]. HW writes lane at base+lane*16,
  // so the wave-uniform LDS base for issue i is elem (i*256 + w*64)*8.
  const int srow = t >> 3;
  const int sseg = t & 7;
  const ushort* aptr = A  + (size_t)(bm * 128 + srow) * K_TOT + sseg * 8;
  const ushort* bptr = Bt + (size_t)(bn * 128 + srow) * K_TOT + sseg * 8;

  for (int kt = 0; kt < K_TOT / 64; ++kt) {
    __syncthreads();  // previous compute done reading LDS
#pragma unroll
    for (int i = 0; i < 4; ++i) {
      load_lds16(aptr + (size_t)i * 32 * K_TOT + kt * 64,
                 &Al[(i * 256 + w * 64) * 8]);
      load_lds16(bptr + (size_t)i * 32 * K_TOT + kt * 64,
                 &Bl[(i * 256 + w * 64) * 8]);
    }
    __syncthreads();  // compiler drains vmcnt(0) before this barrier

#pragma unroll
    for (int kk = 0; kk < 2; ++kk) {
      bf16x8 af[4], bf_[4];
      const int ks = kk * 4 + (lane >> 4);
#pragma unroll
      for (int m = 0; m < 4; ++m)
        af[m] = *reinterpret_cast<const bf16x8*>(
            &Al[(wr * 64 + m * 16 + (lane & 15)) * 64 + ks * 8]);
#pragma unroll
      for (int n = 0; n < 4; ++n)
        bf_[n] = *reinterpret_cast<const bf16x8*>(
            &Bl[(wc * 64 + n * 16 + (lane & 15)) * 64 + ks * 8]);
#pragma unroll
      for (int m = 0; m < 4; ++m)
#pragma unroll
        for (int n = 0; n < 4; ++n)
          acc[m][n] = __builtin_amdgcn_mfma_f32_16x16x32_bf16(
              af[m], bf_[n], acc[m][n], 0, 0, 0);
    }
  }

  // epilogue: C col = lane&15 (+16n), row = (lane>>4)*4 + j (+16m)
  const int colBase = bn * 128 + wc * 64 + (lane & 15);
  const int rowBase = bm * 128 + wr * 64 + ((lane >> 4) << 2);
#pragma unroll
  for (int n = 0; n < 4; ++n) {
    const float bv = bias[colBase + n * 16];
#pragma unroll
    for (int m = 0; m < 4; ++m) {
#pragma unroll
      for (int j = 0; j < 4; ++j) {
        out[(size_t)(rowBase + m * 16 + j) * N_TOT + colBase + n * 16] =
            acc[m][n][j] + bv;
      }
    }
  }
}

// ---------------------------------------------------------------------------
extern "C" void kernel_launch(void* const* d_in, const int* in_sizes, int n_in,
                              void* d_out, int out_size, void* d_ws,
                              size_t ws_size, hipStream_t stream) {
  const int*   words = (const int*)d_in[0];
  const float* E     = (const float*)d_in[1];
  const float* W     = (const float*)d_in[2];
  const float* b     = (const float*)d_in[3];
  float* out = (float*)d_out;

  ushort* Aws  = (ushort*)d_ws;                       // 16384*768 bf16
  ushort* Wtws = Aws + (size_t)M_TOT * K_TOT;         // 512*768 bf16

  hipLaunchKernelGGL(prep_kernel,
                     dim3(M_TOT / 4 + (K_TOT / 64) * (N_TOT / 64)), dim3(256),
                     0, stream, words, E, W, Aws, Wtws);
  hipLaunchKernelGGL(gemm_kernel, dim3((M_TOT / 128) * (N_TOT / 128)),
                     dim3(256), 0, stream, Aws, Wtws, b, out);
}

// Round 3
// 61.214 us; speedup vs baseline: 1.6861x; 1.0208x over previous
//
#include <hip/hip_runtime.h>
#include <hip/hip_bf16.h>

// Problem dims (fixed by reference): B=64 S=256 F=4 V=50257 H=768 D=512
#define M_TOT 16384   // B*S
#define K_TOT 768     // H
#define N_TOT 512     // D

typedef __attribute__((ext_vector_type(8))) __bf16 bf16x8;
typedef __attribute__((ext_vector_type(4))) float f32x4;

static __device__ __forceinline__ ushort f2bf(float x) {
  // round-to-nearest-even bf16 (no NaN inputs here)
  union { float f; unsigned int u; } v; v.f = x;
  unsigned int r = v.u + 0x7fffu + ((v.u >> 16) & 1u);
  return (ushort)(r >> 16);
}

// async global->LDS, 16B per lane; lds dest is wave-uniform base + lane*16
static __device__ __forceinline__ void load_lds16(const ushort* g, ushort* l) {
  __builtin_amdgcn_global_load_lds(
      (const __attribute__((address_space(1))) void*)g,
      (__attribute__((address_space(3))) void*)l, 16, 0, 0);
}

// ---------------------------------------------------------------------------
// Kernel 1 (merged): blocks [0, 4096): gather + masked mean -> bf16 A[16384][768]
//                    blocks [4096, 4192): W[768][512] f32 -> Wt[512][768] bf16
// ---------------------------------------------------------------------------
__global__ __launch_bounds__(256) void prep_kernel(
    const int* __restrict__ words, const float* __restrict__ E,
    const float* __restrict__ W, ushort* __restrict__ A,
    ushort* __restrict__ Wt) {
  const int bid = blockIdx.x;
  const int t = threadIdx.x;
  if (bid < M_TOT / 4) {
    // ---- gather + masked mean: one wave per word row, branchless ----
    // E row 0 is a valid address, so load pads too and FMA with mask; this
    // keeps all 12 L3 loads in one issue run (no wave-uniform branch chain).
    const int row  = bid * 4 + (t >> 6);
    const int lane = t & 63;
    const int4 w4 = *reinterpret_cast<const int4*>(words + (size_t)row * 4);
    const int ids[4] = {w4.x, w4.y, w4.z, w4.w};

    float a[12];
#pragma unroll
    for (int i = 0; i < 12; ++i) a[i] = 0.f;
    float cnt = 0.f;

#pragma unroll
    for (int f = 0; f < 4; ++f) {
      const int id = ids[f];
      const float msk = (id != 0) ? 1.f : 0.f;
      cnt += msk;
      const float4* __restrict__ src =
          reinterpret_cast<const float4*>(E + (size_t)id * K_TOT);
#pragma unroll
      for (int c = 0; c < 3; ++c) {
        const float4 v = src[c * 64 + lane];
        a[c * 4 + 0] += v.x * msk; a[c * 4 + 1] += v.y * msk;
        a[c * 4 + 2] += v.z * msk; a[c * 4 + 3] += v.w * msk;
      }
    }
    const float s = (cnt > 0.f) ? (1.f / cnt) : 0.f;  // fully-padded word -> 0
    ushort* dst = A + (size_t)row * K_TOT;
#pragma unroll
    for (int c = 0; c < 3; ++c) {
      ushort4 o;
      o.x = f2bf(a[c * 4 + 0] * s);
      o.y = f2bf(a[c * 4 + 1] * s);
      o.z = f2bf(a[c * 4 + 2] * s);
      o.w = f2bf(a[c * 4 + 3] * s);
      *reinterpret_cast<ushort4*>(dst + c * 256 + lane * 4) = o;
    }
  } else {
    // ---- transpose + bf16-convert W -> Wt ----
    __shared__ float tile[64][65];
    const int b2 = bid - M_TOT / 4;
    const int k0 = (b2 % (K_TOT / 64)) * 64;
    const int n0 = (b2 / (K_TOT / 64)) * 64;
#pragma unroll
    for (int i = 0; i < 4; ++i) {
      const int idx = t + i * 256;
      const int r = idx >> 4;
      const int c = (idx & 15) * 4;
      const float4 v = *reinterpret_cast<const float4*>(
          W + (size_t)(k0 + r) * N_TOT + n0 + c);
      tile[r][c + 0] = v.x; tile[r][c + 1] = v.y;
      tile[r][c + 2] = v.z; tile[r][c + 3] = v.w;
    }
    __syncthreads();
#pragma unroll
    for (int i = 0; i < 4; ++i) {
      const int idx = t + i * 256;
      const int rn = idx >> 4;
      const int ck = (idx & 15) * 4;
      ushort4 o;
      o.x = f2bf(tile[ck + 0][rn]);
      o.y = f2bf(tile[ck + 1][rn]);
      o.z = f2bf(tile[ck + 2][rn]);
      o.w = f2bf(tile[ck + 3][rn]);
      *reinterpret_cast<ushort4*>(Wt + (size_t)(n0 + rn) * K_TOT + k0 + ck) = o;
    }
  }
}

// ---------------------------------------------------------------------------
// Kernel 2: bf16 MFMA GEMM  out[16384][512] = A @ Wt^T + bias
// 128x128 tile, BK=64, 4 waves, global_load_lds width-16, linear LDS,
// explicit double-buffer 2-phase: STAGE(next) issued BEFORE compute(cur);
// one __syncthreads per iter (compiler's vmcnt(0)+lgkmcnt(0) drain is the
// exact semantic needed: next-tile loads landed, all waves done reading cur).
// ---------------------------------------------------------------------------
__global__ __launch_bounds__(256) void gemm_kernel(
    const ushort* __restrict__ A, const ushort* __restrict__ Bt,
    const float* __restrict__ bias, float* __restrict__ out) {
  __shared__ ushort Al[2][128 * 64];
  __shared__ ushort Bl[2][128 * 64];
  const int t    = threadIdx.x;
  const int lane = t & 63;
  const int w    = t >> 6;
  const int bm   = blockIdx.x >> 2;   // 0..127
  const int bn   = blockIdx.x & 3;    // 0..3
  const int wr   = w >> 1;            // 0..1
  const int wc   = w & 1;             // 0..1

  f32x4 acc[4][4];
#pragma unroll
  for (int m = 0; m < 4; ++m)
#pragma unroll
    for (int n = 0; n < 4; ++n) acc[m][n] = (f32x4){0.f, 0.f, 0.f, 0.f};

  // staging: chunk c = i*256 + t covers row = c>>3 (=i*32 + t>>3), seg = c&7.
  // LDS elem offset = c*8 -> linear [128][64]; wave-uniform base per issue.
  const int srow = t >> 3;
  const int sseg = t & 7;
  const ushort* aptr = A  + (size_t)(bm * 128 + srow) * K_TOT + sseg * 8;
  const ushort* bptr = Bt + (size_t)(bn * 128 + srow) * K_TOT + sseg * 8;

#define STAGE(buf, kt)                                                       \
  do {                                                                       \
    _Pragma("unroll") for (int i = 0; i < 4; ++i) {                          \
      load_lds16(aptr + (size_t)i * 32 * K_TOT + (kt) * 64,                  \
                 &Al[buf][(i * 256 + w * 64) * 8]);                          \
      load_lds16(bptr + (size_t)i * 32 * K_TOT + (kt) * 64,                  \
                 &Bl[buf][(i * 256 + w * 64) * 8]);                          \
    }                                                                        \
  } while (0)

  STAGE(0, 0);
  __syncthreads();  // buf0 staged (vmcnt(0) drained by compiler)

  int cur = 0;
  const int NT = K_TOT / 64;  // 12
  for (int kt = 0; kt < NT; ++kt) {
    if (kt + 1 < NT) {
      if (cur == 0) STAGE(1, kt + 1); else STAGE(0, kt + 1);
    }
#pragma unroll
    for (int kk = 0; kk < 2; ++kk) {
      bf16x8 af[4], bf_[4];
      const int ks = kk * 4 + (lane >> 4);
      const ushort* Ab = cur ? Al[1] : Al[0];
      const ushort* Bb = cur ? Bl[1] : Bl[0];
#pragma unroll
      for (int m = 0; m < 4; ++m)
        af[m] = *reinterpret_cast<const bf16x8*>(
            &Ab[(wr * 64 + m * 16 + (lane & 15)) * 64 + ks * 8]);
#pragma unroll
      for (int n = 0; n < 4; ++n)
        bf_[n] = *reinterpret_cast<const bf16x8*>(
            &Bb[(wc * 64 + n * 16 + (lane & 15)) * 64 + ks * 8]);
      __builtin_amdgcn_s_setprio(1);
#pragma unroll
      for (int m = 0; m < 4; ++m)
#pragma unroll
        for (int n = 0; n < 4; ++n)
          acc[m][n] = __builtin_amdgcn_mfma_f32_16x16x32_bf16(
              af[m], bf_[n], acc[m][n], 0, 0, 0);
      __builtin_amdgcn_s_setprio(0);
    }
    __syncthreads();  // next-tile loads landed; all waves done reading cur
    cur ^= 1;
  }
#undef STAGE

  // epilogue: C col = lane&15 (+16n), row = (lane>>4)*4 + j (+16m)
  // nontemporal: out is never re-read; keep L3 for E.
  const int colBase = bn * 128 + wc * 64 + (lane & 15);
  const int rowBase = bm * 128 + wr * 64 + ((lane >> 4) << 2);
#pragma unroll
  for (int n = 0; n < 4; ++n) {
    const float bv = bias[colBase + n * 16];
#pragma unroll
    for (int m = 0; m < 4; ++m) {
#pragma unroll
      for (int j = 0; j < 4; ++j) {
        __builtin_nontemporal_store(
            acc[m][n][j] + bv,
            &out[(size_t)(rowBase + m * 16 + j) * N_TOT + colBase + n * 16]);
      }
    }
  }
}

// ---------------------------------------------------------------------------
extern "C" void kernel_launch(void* const* d_in, const int* in_sizes, int n_in,
                              void* d_out, int out_size, void* d_ws,
                              size_t ws_size, hipStream_t stream) {
  const int*   words = (const int*)d_in[0];
  const float* E     = (const float*)d_in[1];
  const float* W     = (const float*)d_in[2];
  const float* b     = (const float*)d_in[3];
  float* out = (float*)d_out;

  ushort* Aws  = (ushort*)d_ws;                       // 16384*768 bf16
  ushort* Wtws = Aws + (size_t)M_TOT * K_TOT;         // 512*768 bf16

  hipLaunchKernelGGL(prep_kernel,
                     dim3(M_TOT / 4 + (K_TOT / 64) * (N_TOT / 64)), dim3(256),
                     0, stream, words, E, W, Aws, Wtws);
  hipLaunchKernelGGL(gemm_kernel, dim3((M_TOT / 128) * (N_TOT / 128)),
                     dim3(256), 0, stream, Aws, Wtws, b, out);
}